// Round 1
// baseline (118615.662 us; speedup 1.0000x reference)
//
#include <hip/hip_runtime.h>
#include <stdint.h>

#define NW    284   // per-thread weight dwords (f16 pairs)
#define NW4   71    // NW/4
#define TMAIN 4096
#define TTOT  5120

typedef _Float16 f16;
typedef _Float16 f16x2 __attribute__((ext_vector_type(2)));

static_assert(NW4 * 4 == NW, "NW must be divisible by 4");

__device__ __forceinline__ float fdot2(uint32_t a, uint32_t b, float c) {
  return __builtin_amdgcn_fdot2(__builtin_bit_cast(f16x2, a),
                                __builtin_bit_cast(f16x2, b), c, false);
}
__device__ __forceinline__ uint32_t packf16(float a, float b) {
  f16x2 p = { (_Float16)a, (_Float16)b };
  return __builtin_bit_cast(uint32_t, p);
}
__device__ __forceinline__ float sigm(float x) { return 1.f / (1.f + __expf(-x)); }
__device__ __forceinline__ float tanhfast(float x) { return 2.f / (1.f + __expf(-2.f * x)) - 1.f; }

// H slot map (f16 indices): h1 [0:152) (151+1 pad), h2 [152:408) (251+5 pad), h3 [408:464) (51+5 pad).
// Per-thread weight slots s in [0,568): s<408 = layer-2 row (aligned to H slots);
// tail k=s-408 in [0,160): role depends on thread id (see wslot).
__device__ float wslot(int t, int s,
                       const float* Wih1, const float* Whh1,
                       const float* Wih2, const float* Whh2,
                       const float* Wih3, const float* Whh3,
                       const float* Wl) {
  if (s < 408) {                       // layer-2 gate row t (t<1004)
    if (t >= 1004) return 0.f;
    if (s < 151) return Wih2[t * 151 + s];          // vs h1
    if (s < 152) return 0.f;                        // h1 pad
    int c = s - 152;
    return (c < 251) ? Whh2[t * 251 + c] : 0.f;     // vs h2 (+pad)
  }
  int k = s - 408;
  if (t < 604) {                       // layer-1 gate row t: [x0,x1, h1...]
    if (k < 2) return Wih1[t * 2 + k];
    int c = k - 2;
    return (c < 151) ? Whh1[t * 151 + c] : 0.f;
  }
  if (t < 1012) {                      // layer-3 half-rows: idx pairs split K
    int idx = t - 604, r = idx >> 1, hf = idx & 1;
    if (!hf) return Wih3[r * 251 + k];              // H slots [152:312): h2[0:160)
    if (k >= 152) return 0.f;
    int c = k + 160;                                // H slots [312:464)
    if (c < 251) return Wih3[r * 251 + c];
    if (c < 256) return 0.f;                        // h2 pad
    int c3 = c - 256;
    return (c3 < 51) ? Whh3[r * 51 + c3] : 0.f;     // vs h3 (+pad)
  }
  if (t < 1014) {                      // final linear rows over h3
    int r = t - 1012;
    return (k < 51) ? Wl[r * 51 + k] : 0.f;
  }
  return 0.f;
}

__global__ void prep(const float* __restrict__ x,
                     const float* __restrict__ Wih1, const float* __restrict__ Whh1,
                     const float* __restrict__ Wih2, const float* __restrict__ Whh2,
                     const float* __restrict__ Wih3, const float* __restrict__ Whh3,
                     const float* __restrict__ Wl,
                     uint32_t* __restrict__ ws_w, uint32_t* __restrict__ ws_x) {
  int b = blockIdx.x;
  if (b < 1024) {
    for (int i = threadIdx.x; i < NW; i += blockDim.x) {
      float v0 = wslot(b, 2 * i,     Wih1, Whh1, Wih2, Whh2, Wih3, Whh3, Wl);
      float v1 = wslot(b, 2 * i + 1, Wih1, Whh1, Wih2, Whh2, Wih3, Whh3, Wl);
      ws_w[(size_t)b * NW + i] = packf16(v0, v1);
    }
  } else {
    int i = (b - 1024) * 256 + threadIdx.x;
    if (i < TMAIN) ws_x[i] = packf16(x[2 * i], x[2 * i + 1]);
  }
}

__global__ __launch_bounds__(1024, 1) void lstm_seq(
    const uint32_t* __restrict__ ws_w, const uint32_t* __restrict__ ws_x,
    const float* __restrict__ bih1, const float* __restrict__ bhh1,
    const float* __restrict__ bih2, const float* __restrict__ bhh2,
    const float* __restrict__ bih3, const float* __restrict__ bhh3,
    const float* __restrict__ bl, float* __restrict__ out) {
  __shared__ __align__(16) f16 Hs[464];     // h1|h2|h3, padded, f16
  __shared__ uint32_t XL[TMAIN];            // x as f16 pairs
  __shared__ float G[1024];                 // gate staging
  __shared__ float bs1[604];
  __shared__ float bs2[1004];
  __shared__ float bs3[204];
  __shared__ float bsl[2];
  __shared__ float c1s[151], c2s[251], c3s[51];
  __shared__ uint32_t yfb;                  // feedback y as f16 pair

  const int tid = threadIdx.x;

  uint32_t W[NW];                           // register-resident weights (static-indexed only)
  {
    const uint4* src = (const uint4*)(ws_w + (size_t)tid * NW);
#pragma unroll
    for (int i = 0; i < NW4; ++i) {
      uint4 v = src[i];
      W[4*i+0] = v.x; W[4*i+1] = v.y; W[4*i+2] = v.z; W[4*i+3] = v.w;
    }
  }
#pragma unroll
  for (int i = 0; i < 4; ++i) XL[tid + 1024 * i] = ws_x[tid + 1024 * i];
  if (tid < 604)  bs1[tid] = bih1[tid] + bhh1[tid];
  if (tid < 1004) bs2[tid] = bih2[tid] + bhh2[tid];
  if (tid < 204)  bs3[tid] = bih3[tid] + bhh3[tid];
  if (tid < 2)    bsl[tid] = bl[tid];
  if (tid < 232)  ((uint32_t*)Hs)[tid] = 0u;   // zero all 464 f16 (incl. pads)
  if (tid < 151)  c1s[tid] = 0.f;
  if (tid < 251)  c2s[tid] = 0.f;
  if (tid < 51)   c3s[tid] = 0.f;
  if (tid == 0)   yfb = 0u;
  __syncthreads();

  const uint4* Hp = (const uint4*)Hs;       // broadcast b128 view of activations

#pragma unroll 1
  for (int t = 0; t < TTOT; ++t) {
    // ---- phase 1: layer-1 gates (threads 0..603, one gate row each; reads h1(t-1))
    if (tid < 604) {
      uint32_t xin = (t < TMAIN) ? XL[t] : yfb;
      float g0 = fdot2(W[204], xin, bs1[tid]);
      float g1 = 0.f, g2 = 0.f, g3 = 0.f;
#pragma unroll
      for (int j = 0; j < 19; ++j) {
        uint4 hv = Hp[j];
        g0 = fdot2(W[205+4*j+0], hv.x, g0);
        g1 = fdot2(W[205+4*j+1], hv.y, g1);
        g2 = fdot2(W[205+4*j+2], hv.z, g2);
        g3 = fdot2(W[205+4*j+3], hv.w, g3);
      }
      G[tid] = (g0 + g1) + (g2 + g3);
    }
    __syncthreads();
    // ---- phase 2: layer-1 cell update
    if (tid < 151) {
      float gi = sigm(G[tid]);
      float gf = sigm(G[151 + tid]);
      float gg = tanhfast(G[302 + tid]);
      float go = sigm(G[453 + tid]);
      float c = gf * c1s[tid] + gi * gg;
      c1s[tid] = c;
      Hs[tid] = (f16)(go * tanhfast(c));
    }
    __syncthreads();
    // ---- phase 3: layer-2 gates (threads 0..1003; reads h1(t), h2(t-1))
    if (tid < 1004) {
      float g0 = bs2[tid], g1 = 0.f, g2 = 0.f, g3 = 0.f;
#pragma unroll
      for (int j = 0; j < 51; ++j) {
        uint4 hv = Hp[j];
        g0 = fdot2(W[4*j+0], hv.x, g0);
        g1 = fdot2(W[4*j+1], hv.y, g1);
        g2 = fdot2(W[4*j+2], hv.z, g2);
        g3 = fdot2(W[4*j+3], hv.w, g3);
      }
      G[tid] = (g0 + g1) + (g2 + g3);
    }
    __syncthreads();
    // ---- phase 4: layer-2 cell update
    if (tid < 251) {
      float gi = sigm(G[tid]);
      float gf = sigm(G[251 + tid]);
      float gg = tanhfast(G[502 + tid]);
      float go = sigm(G[753 + tid]);
      float c = gf * c2s[tid] + gi * gg;
      c2s[tid] = c;
      Hs[152 + tid] = (f16)(go * tanhfast(c));
    }
    __syncthreads();
    // ---- phase 5: layer-3 gates, K split over lane pairs (threads 604..1011)
    if (tid >= 604 && tid < 1012) {
      int idx = tid - 604, r = idx >> 1, hf = idx & 1;
      const uint4* hp = Hp + (hf ? 39 : 19);
      float g0 = hf ? 0.f : bs3[r];
      float g1 = 0.f, g2 = 0.f, g3 = 0.f;
#pragma unroll
      for (int j = 0; j < 19; ++j) {
        uint4 hv = hp[j];
        g0 = fdot2(W[204+4*j+0], hv.x, g0);
        g1 = fdot2(W[204+4*j+1], hv.y, g1);
        g2 = fdot2(W[204+4*j+2], hv.z, g2);
        g3 = fdot2(W[204+4*j+3], hv.w, g3);
      }
      if (!hf) {                       // half A has one extra b128 (20 vs 19)
        uint4 hv = Hp[38];
        g0 = fdot2(W[280], hv.x, g0);
        g1 = fdot2(W[281], hv.y, g1);
        g2 = fdot2(W[282], hv.z, g2);
        g3 = fdot2(W[283], hv.w, g3);
      }
      float s = (g0 + g1) + (g2 + g3);
      s += __shfl_xor(s, 1);           // combine K-halves (adjacent lanes)
      if (!hf) G[r] = s;
    }
    __syncthreads();
    // ---- phase 6: layer-3 cell update
    if (tid < 51) {
      float gi = sigm(G[tid]);
      float gf = sigm(G[51 + tid]);
      float gg = tanhfast(G[102 + tid]);
      float go = sigm(G[153 + tid]);
      float c = gf * c3s[tid] + gi * gg;
      c3s[tid] = c;
      Hs[408 + tid] = (f16)(go * tanhfast(c));
    }
    __syncthreads();
    // ---- phase 7: output linear (threads 1012,1013) + feedback
    if (tid >= 1012 && tid < 1014) {
      int r = tid - 1012;
      float g0 = bsl[r], g1 = 0.f, g2 = 0.f, g3 = 0.f;
#pragma unroll
      for (int j = 0; j < 7; ++j) {
        uint4 hv = Hp[51 + j];
        g0 = fdot2(W[204+4*j+0], hv.x, g0);
        g1 = fdot2(W[204+4*j+1], hv.y, g1);
        g2 = fdot2(W[204+4*j+2], hv.z, g2);
        g3 = fdot2(W[204+4*j+3], hv.w, g3);
      }
      float y = (g0 + g1) + (g2 + g3);
      out[2 * t + r] = y;
      float yo = __shfl_down(y, 1);
      if (r == 0) yfb = packf16(y, yo);
    }
    __syncthreads();
  }
}

extern "C" void kernel_launch(void* const* d_in, const int* in_sizes, int n_in,
                              void* d_out, int out_size, void* d_ws, size_t ws_size,
                              hipStream_t stream) {
  (void)in_sizes; (void)n_in; (void)out_size; (void)ws_size;
  const float* x    = (const float*)d_in[0];
  const float* Wih1 = (const float*)d_in[1];
  const float* Whh1 = (const float*)d_in[2];
  const float* bih1 = (const float*)d_in[3];
  const float* bhh1 = (const float*)d_in[4];
  const float* Wih2 = (const float*)d_in[5];
  const float* Whh2 = (const float*)d_in[6];
  const float* bih2 = (const float*)d_in[7];
  const float* bhh2 = (const float*)d_in[8];
  const float* Wih3 = (const float*)d_in[9];
  const float* Whh3 = (const float*)d_in[10];
  const float* bih3 = (const float*)d_in[11];
  const float* bhh3 = (const float*)d_in[12];
  const float* Wl   = (const float*)d_in[13];
  const float* bl   = (const float*)d_in[14];

  uint32_t* ws_w = (uint32_t*)d_ws;           // 1024 * 284 dwords
  uint32_t* ws_x = ws_w + 1024 * NW;          // 4096 dwords

  prep<<<1040, 256, 0, stream>>>(x, Wih1, Whh1, Wih2, Whh2, Wih3, Whh3, Wl, ws_w, ws_x);
  lstm_seq<<<1, 1024, 0, stream>>>(ws_w, ws_x, bih1, bhh1, bih2, bhh2, bih3, bhh3,
                                   bl, (float*)d_out);
}